// Round 5
// baseline (181.896 us; speedup 1.0000x reference)
//
#include <hip/hip_runtime.h>
#include <hip/hip_bf16.h>

// Fused WindowAttention: x @ W_qkv + b -> MHA(16 heads, D=64) -> @ W_proj + b
// B=8, N=1024, C=1024. fp32 in/out; internal bf16 MFMA + fp32 accum.
//
// Pipeline:
//   1. convert_f32_bf16 : X fp32 -> Xb bf16
//   2. transpose_w x2   : W_qkv -> Wqt [3072][1024] bf16, W_proj -> Wpt bf16
//   3. qkv_gemm2 -> Q,K,V bf16 [B*H][N][64] (row-major, cheap stores)
//   4. v_transpose      : V [bh][n][64] -> VtG [bh][64][n]
//   5. attn_kernel v4: swapped QK^T, double-buffered K/V^T gload_lds staging
//      (counted vmcnt + raw barriers), XCD-local grid, defer-max
//   6. proj_gemm2 -> fp32 d_out

using bf16x8 = __attribute__((ext_vector_type(8))) short;
using f32x4  = __attribute__((ext_vector_type(4))) float;
using u16    = unsigned short;
using u16x4  = __attribute__((ext_vector_type(4))) unsigned short;
using u16x8  = __attribute__((ext_vector_type(8))) unsigned short;

__device__ __forceinline__ u16 f2bf(float f) {
  unsigned int u = __float_as_uint(f);
  u += 0x7FFFu + ((u >> 16) & 1u);   // RNE (finite inputs only)
  return (u16)(u >> 16);
}
__device__ __forceinline__ float bf2f(u16 h) {
  return __uint_as_float(((unsigned int)h) << 16);
}

__device__ __forceinline__ void gload16(const u16* g, u16* lbase, int lane) {
#if __has_builtin(__builtin_amdgcn_global_load_lds)
  __builtin_amdgcn_global_load_lds(
      (const __attribute__((address_space(1))) void*)g,
      (__attribute__((address_space(3))) void*)lbase, 16, 0, 0);
#else
  *(u16x8*)(lbase + (size_t)lane * 8) = *(const u16x8*)g;
#endif
}

// ---------------------------------------------------------------------------
__global__ __launch_bounds__(256) void convert_f32_bf16(
    const float* __restrict__ in, u16* __restrict__ out)
{
  size_t i = ((size_t)blockIdx.x * 256 + threadIdx.x) * 8;
  f32x4 a = *(const f32x4*)(in + i);
  f32x4 b = *(const f32x4*)(in + i + 4);
  u16x8 h = { f2bf(a.x), f2bf(a.y), f2bf(a.z), f2bf(a.w),
              f2bf(b.x), f2bf(b.y), f2bf(b.z), f2bf(b.w) };
  *(u16x8*)(out + i) = h;
}

// ---------------------------------------------------------------------------
__global__ __launch_bounds__(256) void transpose_w(
    const float* __restrict__ W, u16* __restrict__ Wt, int K, int N)
{
  __shared__ float T[64][65];
  const int t = threadIdx.x;
  const int n0 = blockIdx.x * 64, k0 = blockIdx.y * 64;
  const int r = t >> 4, c4 = (t & 15) * 4;
  #pragma unroll
  for (int i = 0; i < 4; ++i) {
    f32x4 v = *(const f32x4*)&W[(size_t)(k0 + r + i * 16) * N + n0 + c4];
    T[r + i * 16][c4 + 0] = v.x;
    T[r + i * 16][c4 + 1] = v.y;
    T[r + i * 16][c4 + 2] = v.z;
    T[r + i * 16][c4 + 3] = v.w;
  }
  __syncthreads();
  const int nr = t >> 2, cs = (t & 3) * 16;
  u16x8 h0, h1;
  #pragma unroll
  for (int j = 0; j < 8; ++j) h0[j] = f2bf(T[cs + j][nr]);
  #pragma unroll
  for (int j = 0; j < 8; ++j) h1[j] = f2bf(T[cs + 8 + j][nr]);
  u16* dst = Wt + (size_t)(n0 + nr) * K + k0 + cs;
  *(u16x8*)dst = h0;
  *(u16x8*)(dst + 8) = h1;
}

// ---------------------------------------------------------------------------
// V transpose: Vr [bh][1024][64] -> Vt [bh][64][1024]. One 64x64 tile/block.
// ---------------------------------------------------------------------------
__global__ __launch_bounds__(256) void v_transpose(
    const u16* __restrict__ Vr, u16* __restrict__ Vt)
{
  __shared__ u16 T[64 * 70];   // stride 70: rows spread over banks (35 odd)
  const int bh = blockIdx.x >> 4, nc = blockIdx.x & 15;
  const int t = threadIdx.x;
  const int r = t >> 2, c = (t & 3) * 16;
  const u16* src = Vr + ((size_t)bh * 1024 + nc * 64 + r) * 64 + c;
  *(u16x8*)&T[r * 70 + c]     = *(const u16x8*)src;
  *(u16x8*)&T[r * 70 + c + 8] = *(const u16x8*)(src + 8);
  __syncthreads();
  const int d = t >> 2, n0 = (t & 3) * 16;
  u16x8 o0, o1;
  #pragma unroll
  for (int j = 0; j < 8; ++j) o0[j] = T[(n0 + j) * 70 + d];
  #pragma unroll
  for (int j = 0; j < 8; ++j) o1[j] = T[(n0 + 8 + j) * 70 + d];
  u16* dst = Vt + ((size_t)bh * 64 + d) * 1024 + nc * 64 + n0;
  *(u16x8*)dst = o0;
  *(u16x8*)(dst + 8) = o1;
}

// ---------------------------------------------------------------------------
// QKV GEMM (m97 structure). Q,K,V all row-major [bh][n][64] (r2 epilogue).
// ---------------------------------------------------------------------------
__global__ __launch_bounds__(256, 2) void qkv_gemm2(
    const u16* __restrict__ Xb, const u16* __restrict__ Wt,
    const float* __restrict__ bias,
    u16* __restrict__ Qb, u16* __restrict__ Kb, u16* __restrict__ Vr)
{
  constexpr int KD = 1024;
  __shared__ __align__(16) u16 As[128 * 32];
  __shared__ __align__(16) u16 Bs[128 * 32];

  const int tid = threadIdx.x;
  const int lane = tid & 63, wid = tid >> 6;
  const int wr = wid >> 1, wc = wid & 1;
  const int lg = lane >> 4, lc = lane & 15;
  const int row0 = blockIdx.x * 128, col0 = blockIdx.y * 128;

  f32x4 acc[4][4];
  #pragma unroll
  for (int m = 0; m < 4; ++m)
    #pragma unroll
    for (int n = 0; n < 4; ++n) acc[m][n] = (f32x4){0.f, 0.f, 0.f, 0.f};

  const int l4 = lane >> 2, ls = (lane & 3) * 8;
  const u16* gA0 = Xb + (size_t)(row0 + wid * 16 + l4) * KD + ls;
  const u16* gB0 = Wt + (size_t)(col0 + wid * 16 + l4) * KD + ls;
  u16* lA0 = As + wid * 512;
  u16* lB0 = Bs + wid * 512;

  for (int k0 = 0; k0 < KD; k0 += 32) {
    gload16(gA0 + k0, lA0, lane);
    gload16(gA0 + 64 * KD + k0, lA0 + 2048, lane);
    gload16(gB0 + k0, lB0, lane);
    gload16(gB0 + 64 * KD + k0, lB0 + 2048, lane);
    __syncthreads();

    bf16x8 a[4], b[4];
    #pragma unroll
    for (int m = 0; m < 4; ++m)
      a[m] = *(const bf16x8*)(As + (wr * 64 + m * 16 + lc) * 32 + lg * 8);
    #pragma unroll
    for (int n = 0; n < 4; ++n)
      b[n] = *(const bf16x8*)(Bs + (wc * 64 + n * 16 + lc) * 32 + lg * 8);
    #pragma unroll
    for (int m = 0; m < 4; ++m)
      #pragma unroll
      for (int n = 0; n < 4; ++n)
        acc[m][n] = __builtin_amdgcn_mfma_f32_16x16x32_bf16(a[m], b[n], acc[m][n], 0, 0, 0);
    __syncthreads();
  }

  #pragma unroll
  for (int m = 0; m < 4; ++m) {
    #pragma unroll
    for (int n = 0; n < 4; ++n) {
      const int gcb = col0 + wc * 64 + n * 16;     // block-uniform channel base
      const int which = gcb >> 10;
      const int gc = gcb + lc;
      const float bv = bias[gc];
      const int ci = gc & 1023, h = ci >> 6, d = ci & 63;
      const int gr0 = row0 + wr * 64 + m * 16 + lg * 4;
      const int bb = gr0 >> 10, nn0 = gr0 & 1023;
      u16* dst = (which == 0) ? Qb : (which == 1) ? Kb : Vr;
      #pragma unroll
      for (int r = 0; r < 4; ++r)
        dst[((size_t)(bb * 16 + h) * 1024 + nn0 + r) * 64 + d] =
            f2bf(acc[m][n][r] + bv);
    }
  }
}

// ---------------------------------------------------------------------------
// Flash attention v4. Block = 128 q-rows of one (b,h); 4 waves x 32 rows.
// Grid (bh=128, qt=8): id%8 = bh%8 -> all q-tiles of a head on one XCD.
// K and V^T double-buffered via global_load_lds with counted vmcnt + raw
// barriers (prefetch stays in flight across the barrier). Pre-swizzled
// source slots (slot ^= row&7); reads apply the same XOR. Defer-max THR=8.
// ---------------------------------------------------------------------------
__global__ __launch_bounds__(256, 2) void attn_kernel(
    const u16* __restrict__ Q, const u16* __restrict__ K,
    const u16* __restrict__ Vt, u16* __restrict__ O)
{
  __shared__ __align__(16) u16 Ks[2 * 64 * 64];   // dbuf [key][d] swizzled
  __shared__ __align__(16) u16 Vs[2 * 64 * 64];   // dbuf [d][key] swizzled
  __shared__ __align__(16) u16 Pl[4 * 32 * 72];   // per-wave [qrow][key]

  const int tid = threadIdx.x, lane = tid & 63, wid = tid >> 6;
  const int lg = lane >> 4, lc = lane & 15;
  const int bh = blockIdx.x;       // [0,128)
  const int qt = blockIdx.y;       // [0,8)
  const size_t base = (size_t)bh * 65536;
  const u16* Qp = Q + base;
  const u16* Kp = K + base;
  const u16* Vp = Vt + base;       // [64][1024]

  // staging geometry: wave w stages rows [w*16, w*16+16) of each tile.
  const int srow  = lane >> 3;               // 0..7
  const int sslot = (lane & 7) ^ srow;       // pre-swizzled 16B slot
  const u16* gK0 = Kp + (size_t)(wid * 16 + srow) * 64 + sslot * 8;
  const u16* gV0 = Vp + (size_t)(wid * 16 + srow) * 1024 + sslot * 8;
  u16* lK0 = Ks + wid * 1024;
  u16* lV0 = Vs + wid * 1024;

  // prologue: stage tile 0 into buffer 0 (4 outstanding VMEM)
  gload16(gK0, lK0, lane);
  gload16(gK0 + 512, lK0 + 512, lane);
  gload16(gV0, lV0, lane);
  gload16(gV0 + 8192, lV0 + 512, lane);

  // Q fragments (B-operand), pre-scaled by 0.125
  bf16x8 qf[2][2];
  #pragma unroll
  for (int f = 0; f < 2; ++f) {
    const u16* qsrc = Qp + (size_t)(qt * 128 + wid * 32 + f * 16 + lc) * 64 + lg * 8;
    #pragma unroll
    for (int ks = 0; ks < 2; ++ks) {
      u16x8 raw = *(const u16x8*)(qsrc + ks * 32);
      bf16x8 t;
      #pragma unroll
      for (int j = 0; j < 8; ++j) t[j] = (short)f2bf(bf2f(raw[j]) * 0.125f);
      qf[f][ks] = t;
    }
  }

  f32x4 o[2][4];
  #pragma unroll
  for (int f = 0; f < 2; ++f)
    #pragma unroll
    for (int d = 0; d < 4; ++d) o[f][d] = (f32x4){0.f, 0.f, 0.f, 0.f};
  float m_r[2] = {-1e30f, -1e30f};
  float l_r[2] = {0.f, 0.f};

  // read-side swizzled column offsets (elems): slot = ks*4+lg, xor row&7=lc&7
  const int xr = lc & 7;
  const int cof0 = ((0 + lg) ^ xr) * 8;
  const int cof1 = ((4 + lg) ^ xr) * 8;
  const int prow = (wid * 32 + lc) * 72;

  for (int kt = 0; kt < 16; ++kt) {
    const int cOff = (kt & 1) * 4096;
    const int nOff = cOff ^ 4096;
    if (kt < 15) {
      // prefetch next tile into the other buffer (stays in flight)
      gload16(gK0 + (kt + 1) * 4096,       lK0 + nOff,       lane);
      gload16(gK0 + (kt + 1) * 4096 + 512, lK0 + nOff + 512, lane);
      gload16(gV0 + (kt + 1) * 64,         lV0 + nOff,       lane);
      gload16(gV0 + (kt + 1) * 64 + 8192,  lV0 + nOff + 512, lane);
      asm volatile("s_waitcnt vmcnt(4)" ::: "memory");  // current tile done
    } else {
      asm volatile("s_waitcnt vmcnt(0)" ::: "memory");
    }
    __builtin_amdgcn_s_barrier();
    __builtin_amdgcn_sched_barrier(0);

    // S^T = K @ Q : lane holds q-row f*16+lc, keys kb*16 + lg*4 + c
    f32x4 s[2][4];
    #pragma unroll
    for (int f = 0; f < 2; ++f)
      #pragma unroll
      for (int kb = 0; kb < 4; ++kb) s[f][kb] = (f32x4){0.f, 0.f, 0.f, 0.f};
    #pragma unroll
    for (int ks = 0; ks < 2; ++ks) {
      const int co = ks ? cof1 : cof0;
      #pragma unroll
      for (int kb = 0; kb < 4; ++kb) {
        bf16x8 kfr = *(const bf16x8*)(Ks + cOff + (kb * 16 + lc) * 64 + co);
        s[0][kb] = __builtin_amdgcn_mfma_f32_16x16x32_bf16(kfr, qf[0][ks], s[0][kb], 0, 0, 0);
        s[1][kb] = __builtin_amdgcn_mfma_f32_16x16x32_bf16(kfr, qf[1][ks], s[1][kb], 0, 0, 0);
      }
    }

    // online softmax with defer-max; P pack+store to per-wave LDS
    #pragma unroll
    for (int f = 0; f < 2; ++f) {
      f32x4 t01, t23;
      #pragma unroll
      for (int c = 0; c < 4; ++c) {
        t01[c] = fmaxf(s[f][0][c], s[f][1][c]);
        t23[c] = fmaxf(s[f][2][c], s[f][3][c]);
      }
      float t = fmaxf(fmaxf(fmaxf(t01[0], t01[1]), fmaxf(t01[2], t01[3])),
                      fmaxf(fmaxf(t23[0], t23[1]), fmaxf(t23[2], t23[3])));
      t = fmaxf(t, __shfl_xor(t, 16));
      t = fmaxf(t, __shfl_xor(t, 32));

      if (!__all((t - m_r[f]) <= 8.0f)) {            // max grew: rescale
        float nm = fmaxf(m_r[f], t);
        float sc = __expf(m_r[f] - nm);
        m_r[f] = nm;
        l_r[f] *= sc;
        #pragma unroll
        for (int r = 0; r < 4; ++r) {
          float scr = __shfl(sc, lg * 4 + r, 16);
          #pragma unroll
          for (int d = 0; d < 4; ++d) o[f][d][r] *= scr;
        }
      }

      float lsum = 0.f;
      #pragma unroll
      for (int kb = 0; kb < 4; ++kb) {
        f32x4 p;
        #pragma unroll
        for (int c = 0; c < 4; ++c) {
          p[c] = __expf(s[f][kb][c] - m_r[f]);
          lsum += p[c];
        }
        unsigned w0 = (unsigned)f2bf(p[0]) | ((unsigned)f2bf(p[1]) << 16);
        unsigned w1 = (unsigned)f2bf(p[2]) | ((unsigned)f2bf(p[3]) << 16);
        int pe = prow + f * 16 * 72 + kb * 16 + lg * 4;
        *(unsigned*)(Pl + pe)     = w0;
        *(unsigned*)(Pl + pe + 2) = w1;
      }
      lsum += __shfl_xor(lsum, 16);
      lsum += __shfl_xor(lsum, 32);
      l_r[f] += lsum;
    }

    // drain P writes (same-wave LDS); fence compiler reordering
    asm volatile("s_waitcnt lgkmcnt(0)" ::: "memory");
    __builtin_amdgcn_sched_barrier(0);

    // PV: O += P @ V^T-frags
    bf16x8 pa[2][2];
    #pragma unroll
    for (int f = 0; f < 2; ++f)
      #pragma unroll
      for (int ks = 0; ks < 2; ++ks)
        pa[f][ks] = *(const bf16x8*)(Pl + prow + f * 16 * 72 + ks * 32 + lg * 8);
    #pragma unroll
    for (int d = 0; d < 4; ++d) {
      #pragma unroll
      for (int ks = 0; ks < 2; ++ks) {
        const int co = ks ? cof1 : cof0;
        bf16x8 vfr = *(const bf16x8*)(Vs + cOff + (d * 16 + lc) * 64 + co);
        o[0][d] = __builtin_amdgcn_mfma_f32_16x16x32_bf16(pa[0][ks], vfr, o[0][d], 0, 0, 0);
        o[1][d] = __builtin_amdgcn_mfma_f32_16x16x32_bf16(pa[1][ks], vfr, o[1][d], 0, 0, 0);
      }
    }
    // all waves done reading buf[cur] before next iter overwrites it
    __builtin_amdgcn_s_barrier();
    __builtin_amdgcn_sched_barrier(0);
  }

  // finalize + store bf16 [B][N][C]
  const int b = bh >> 4, h = bh & 15;
  #pragma unroll
  for (int f = 0; f < 2; ++f) {
    float linv = 1.0f / l_r[f];
    #pragma unroll
    for (int r = 0; r < 4; ++r) {
      float li = __shfl(linv, lg * 4 + r, 16);
      int n = qt * 128 + wid * 32 + f * 16 + lg * 4 + r;
      u16* dst = O + ((size_t)b * 1024 + n) * 1024 + h * 64 + lc;
      #pragma unroll
      for (int d = 0; d < 4; ++d) dst[d * 16] = f2bf(o[f][d][r] * li);
    }
  }
}

// ---------------------------------------------------------------------------
// Projection GEMM (m97 structure), unchanged.
// ---------------------------------------------------------------------------
__global__ __launch_bounds__(256, 2) void proj_gemm2(
    const u16* __restrict__ Ab, const u16* __restrict__ Wt,
    const float* __restrict__ bias, float* __restrict__ Out)
{
  constexpr int KD = 1024, NCOL = 1024;
  __shared__ __align__(16) u16 As[128 * 32];
  __shared__ __align__(16) u16 Bs[128 * 32];

  const int tid = threadIdx.x;
  const int lane = tid & 63, wid = tid >> 6;
  const int wr = wid >> 1, wc = wid & 1;
  const int lg = lane >> 4, lc = lane & 15;
  const int row0 = blockIdx.x * 128, col0 = blockIdx.y * 128;

  f32x4 acc[4][4];
  #pragma unroll
  for (int m = 0; m < 4; ++m)
    #pragma unroll
    for (int n = 0; n < 4; ++n) acc[m][n] = (f32x4){0.f, 0.f, 0.f, 0.f};

  const int l4 = lane >> 2, ls = (lane & 3) * 8;
  const u16* gA0 = Ab + (size_t)(row0 + wid * 16 + l4) * KD + ls;
  const u16* gB0 = Wt + (size_t)(col0 + wid * 16 + l4) * KD + ls;
  u16* lA0 = As + wid * 512;
  u16* lB0 = Bs + wid * 512;

  for (int k0 = 0; k0 < KD; k0 += 32) {
    gload16(gA0 + k0, lA0, lane);
    gload16(gA0 + 64 * KD + k0, lA0 + 2048, lane);
    gload16(gB0 + k0, lB0, lane);
    gload16(gB0 + 64 * KD + k0, lB0 + 2048, lane);
    __syncthreads();

    bf16x8 a[4], b[4];
    #pragma unroll
    for (int m = 0; m < 4; ++m)
      a[m] = *(const bf16x8*)(As + (wr * 64 + m * 16 + lc) * 32 + lg * 8);
    #pragma unroll
    for (int n = 0; n < 4; ++n)
      b[n] = *(const bf16x8*)(Bs + (wc * 64 + n * 16 + lc) * 32 + lg * 8);
    #pragma unroll
    for (int m = 0; m < 4; ++m)
      #pragma unroll
      for (int n = 0; n < 4; ++n)
        acc[m][n] = __builtin_amdgcn_mfma_f32_16x16x32_bf16(a[m], b[n], acc[m][n], 0, 0, 0);
    __syncthreads();
  }

  #pragma unroll
  for (int m = 0; m < 4; ++m) {
    #pragma unroll
    for (int n = 0; n < 4; ++n) {
      #pragma unroll
      for (int r = 0; r < 4; ++r) {
        int gr = row0 + wr * 64 + m * 16 + lg * 4 + r;
        int gc = col0 + wc * 64 + n * 16 + lc;
        Out[(size_t)gr * NCOL + gc] = acc[m][n][r] + bias[gc];
      }
    }
  }
}

// ---------------------------------------------------------------------------
extern "C" void kernel_launch(void* const* d_in, const int* in_sizes, int n_in,
                              void* d_out, int out_size, void* d_ws, size_t ws_size,
                              hipStream_t stream) {
  const float* x     = (const float*)d_in[0];
  const float* W_qkv = (const float*)d_in[1];
  const float* b_qkv = (const float*)d_in[2];
  const float* W_prj = (const float*)d_in[3];
  const float* b_prj = (const float*)d_in[4];
  float* out = (float*)d_out;

  const size_t SEG = (size_t)8192 * 1024;   // 8388608 elems (u16)
  char* ws = (char*)d_ws;                   // needs ~59 MiB
  u16* Xb  = (u16*)ws;                      // [0, 16.78M) dead after qkv
  u16* Ab  = Xb;                            // alias: attn output
  u16* VtG = (u16*)(ws + SEG * 2);          // [16.78, 33.55M) V^T [bh][64][1024]
  u16* Wqt = (u16*)(ws + SEG * 4);          // [33.55, 39.85M)
  u16* Wpt = Wqt + (size_t)3072 * 1024;     // [39.85, 41.94M)
  u16* Vr  = (u16*)(ws + 41943040);         // [41.94, 58.72M) V row-major
  u16* Qb  = (u16*)d_out;                   // d_out as scratch
  u16* Kb  = Qb + SEG;

  convert_f32_bf16<<<4096, 256, 0, stream>>>(x, Xb);
  transpose_w<<<dim3(48, 16), 256, 0, stream>>>(W_qkv, Wqt, 1024, 3072);
  transpose_w<<<dim3(16, 16), 256, 0, stream>>>(W_prj, Wpt, 1024, 1024);
  qkv_gemm2<<<dim3(64, 24), 256, 0, stream>>>(Xb, Wqt, b_qkv, Qb, Kb, Vr);
  v_transpose<<<2048, 256, 0, stream>>>(Vr, VtG);
  attn_kernel<<<dim3(128, 8), 256, 0, stream>>>(Qb, Kb, VtG, Ab);
  proj_gemm2<<<dim3(64, 8), 256, 0, stream>>>(Ab, Wpt, b_prj, out);
}

// Round 6
// 167.137 us; speedup vs baseline: 1.0883x; 1.0883x over previous
//
#include <hip/hip_runtime.h>
#include <hip/hip_bf16.h>

// Fused WindowAttention: x @ W_qkv + b -> MHA(16 heads, D=64) -> @ W_proj + b
// B=8, N=1024, C=1024. fp32 in/out; internal bf16 MFMA + fp32 accum.
//
// Pipeline:
//   1. convert_f32_bf16 : X fp32 -> Xb bf16
//   2. transpose_w x2   : W_qkv -> Wqt [3072][1024] bf16, W_proj -> Wpt bf16
//   3. qkv_gemm2 -> Q,K,V bf16 [B*H][N][64] (row-major, cheap stores)
//   4. v_transpose      : V [bh][n][64] -> VtG [bh][64][n]
//   5. attn_kernel v5: swapped QK^T, single-buffer gload_lds staging,
//      XCD-local grid, log2-domain softmax, cvt_pk P-pack, defer-max
//   6. proj_gemm2 -> fp32 d_out

using bf16x8 = __attribute__((ext_vector_type(8))) short;
using f32x4  = __attribute__((ext_vector_type(4))) float;
using u16    = unsigned short;
using u16x4  = __attribute__((ext_vector_type(4))) unsigned short;
using u16x8  = __attribute__((ext_vector_type(8))) unsigned short;
using u32x2  = __attribute__((ext_vector_type(2))) unsigned int;

__device__ __forceinline__ u16 f2bf(float f) {
  unsigned int u = __float_as_uint(f);
  u += 0x7FFFu + ((u >> 16) & 1u);   // RNE (finite inputs only)
  return (u16)(u >> 16);
}
__device__ __forceinline__ float bf2f(u16 h) {
  return __uint_as_float(((unsigned int)h) << 16);
}
__device__ __forceinline__ unsigned cvt_pk_bf16(float a, float b) {
  unsigned r;
  asm("v_cvt_pk_bf16_f32 %0, %1, %2" : "=v"(r) : "v"(a), "v"(b));
  return r;   // low16 = bf16(a), high16 = bf16(b)
}
__device__ __forceinline__ float fexp2(float x) {
#if __has_builtin(__builtin_amdgcn_exp2f)
  return __builtin_amdgcn_exp2f(x);
#else
  return exp2f(x);
#endif
}

__device__ __forceinline__ void gload16(const u16* g, u16* lbase, int lane) {
#if __has_builtin(__builtin_amdgcn_global_load_lds)
  __builtin_amdgcn_global_load_lds(
      (const __attribute__((address_space(1))) void*)g,
      (__attribute__((address_space(3))) void*)lbase, 16, 0, 0);
#else
  *(u16x8*)(lbase + (size_t)lane * 8) = *(const u16x8*)g;
#endif
}

// ---------------------------------------------------------------------------
__global__ __launch_bounds__(256) void convert_f32_bf16(
    const float* __restrict__ in, u16* __restrict__ out)
{
  size_t i = ((size_t)blockIdx.x * 256 + threadIdx.x) * 8;
  f32x4 a = *(const f32x4*)(in + i);
  f32x4 b = *(const f32x4*)(in + i + 4);
  u16x8 h = { f2bf(a.x), f2bf(a.y), f2bf(a.z), f2bf(a.w),
              f2bf(b.x), f2bf(b.y), f2bf(b.z), f2bf(b.w) };
  *(u16x8*)(out + i) = h;
}

// ---------------------------------------------------------------------------
__global__ __launch_bounds__(256) void transpose_w(
    const float* __restrict__ W, u16* __restrict__ Wt, int K, int N)
{
  __shared__ float T[64][65];
  const int t = threadIdx.x;
  const int n0 = blockIdx.x * 64, k0 = blockIdx.y * 64;
  const int r = t >> 4, c4 = (t & 15) * 4;
  #pragma unroll
  for (int i = 0; i < 4; ++i) {
    f32x4 v = *(const f32x4*)&W[(size_t)(k0 + r + i * 16) * N + n0 + c4];
    T[r + i * 16][c4 + 0] = v.x;
    T[r + i * 16][c4 + 1] = v.y;
    T[r + i * 16][c4 + 2] = v.z;
    T[r + i * 16][c4 + 3] = v.w;
  }
  __syncthreads();
  const int nr = t >> 2, cs = (t & 3) * 16;
  u16x8 h0, h1;
  #pragma unroll
  for (int j = 0; j < 8; ++j) h0[j] = f2bf(T[cs + j][nr]);
  #pragma unroll
  for (int j = 0; j < 8; ++j) h1[j] = f2bf(T[cs + 8 + j][nr]);
  u16* dst = Wt + (size_t)(n0 + nr) * K + k0 + cs;
  *(u16x8*)dst = h0;
  *(u16x8*)(dst + 8) = h1;
}

// ---------------------------------------------------------------------------
// V transpose: Vr [bh][1024][64] -> Vt [bh][64][1024]. One 64x64 tile/block.
// ---------------------------------------------------------------------------
__global__ __launch_bounds__(256) void v_transpose(
    const u16* __restrict__ Vr, u16* __restrict__ Vt)
{
  __shared__ u16 T[64 * 70];
  const int bh = blockIdx.x >> 4, nc = blockIdx.x & 15;
  const int t = threadIdx.x;
  const int r = t >> 2, c = (t & 3) * 16;
  const u16* src = Vr + ((size_t)bh * 1024 + nc * 64 + r) * 64 + c;
  *(u16x8*)&T[r * 70 + c]     = *(const u16x8*)src;
  *(u16x8*)&T[r * 70 + c + 8] = *(const u16x8*)(src + 8);
  __syncthreads();
  const int d = t >> 2, n0 = (t & 3) * 16;
  u16x8 o0, o1;
  #pragma unroll
  for (int j = 0; j < 8; ++j) o0[j] = T[(n0 + j) * 70 + d];
  #pragma unroll
  for (int j = 0; j < 8; ++j) o1[j] = T[(n0 + 8 + j) * 70 + d];
  u16* dst = Vt + ((size_t)bh * 64 + d) * 1024 + nc * 64 + n0;
  *(u16x8*)dst = o0;
  *(u16x8*)(dst + 8) = o1;
}

// ---------------------------------------------------------------------------
// QKV GEMM (m97 structure). Q,K,V all row-major [bh][n][64].
// ---------------------------------------------------------------------------
__global__ __launch_bounds__(256, 2) void qkv_gemm2(
    const u16* __restrict__ Xb, const u16* __restrict__ Wt,
    const float* __restrict__ bias,
    u16* __restrict__ Qb, u16* __restrict__ Kb, u16* __restrict__ Vr)
{
  constexpr int KD = 1024;
  __shared__ __align__(16) u16 As[128 * 32];
  __shared__ __align__(16) u16 Bs[128 * 32];

  const int tid = threadIdx.x;
  const int lane = tid & 63, wid = tid >> 6;
  const int wr = wid >> 1, wc = wid & 1;
  const int lg = lane >> 4, lc = lane & 15;
  const int row0 = blockIdx.x * 128, col0 = blockIdx.y * 128;

  f32x4 acc[4][4];
  #pragma unroll
  for (int m = 0; m < 4; ++m)
    #pragma unroll
    for (int n = 0; n < 4; ++n) acc[m][n] = (f32x4){0.f, 0.f, 0.f, 0.f};

  const int l4 = lane >> 2, ls = (lane & 3) * 8;
  const u16* gA0 = Xb + (size_t)(row0 + wid * 16 + l4) * KD + ls;
  const u16* gB0 = Wt + (size_t)(col0 + wid * 16 + l4) * KD + ls;
  u16* lA0 = As + wid * 512;
  u16* lB0 = Bs + wid * 512;

  for (int k0 = 0; k0 < KD; k0 += 32) {
    gload16(gA0 + k0, lA0, lane);
    gload16(gA0 + 64 * KD + k0, lA0 + 2048, lane);
    gload16(gB0 + k0, lB0, lane);
    gload16(gB0 + 64 * KD + k0, lB0 + 2048, lane);
    __syncthreads();

    bf16x8 a[4], b[4];
    #pragma unroll
    for (int m = 0; m < 4; ++m)
      a[m] = *(const bf16x8*)(As + (wr * 64 + m * 16 + lc) * 32 + lg * 8);
    #pragma unroll
    for (int n = 0; n < 4; ++n)
      b[n] = *(const bf16x8*)(Bs + (wc * 64 + n * 16 + lc) * 32 + lg * 8);
    #pragma unroll
    for (int m = 0; m < 4; ++m)
      #pragma unroll
      for (int n = 0; n < 4; ++n)
        acc[m][n] = __builtin_amdgcn_mfma_f32_16x16x32_bf16(a[m], b[n], acc[m][n], 0, 0, 0);
    __syncthreads();
  }

  #pragma unroll
  for (int m = 0; m < 4; ++m) {
    #pragma unroll
    for (int n = 0; n < 4; ++n) {
      const int gcb = col0 + wc * 64 + n * 16;
      const int which = gcb >> 10;
      const int gc = gcb + lc;
      const float bv = bias[gc];
      const int ci = gc & 1023, h = ci >> 6, d = ci & 63;
      const int gr0 = row0 + wr * 64 + m * 16 + lg * 4;
      const int bb = gr0 >> 10, nn0 = gr0 & 1023;
      u16* dst = (which == 0) ? Qb : (which == 1) ? Kb : Vr;
      #pragma unroll
      for (int r = 0; r < 4; ++r)
        dst[((size_t)(bb * 16 + h) * 1024 + nn0 + r) * 64 + d] =
            f2bf(acc[m][n][r] + bv);
    }
  }
}

// ---------------------------------------------------------------------------
// Flash attention v5. Block = 128 q-rows of one (b,h); 4 waves x 32 rows.
// Grid (bh=128, qt=8): id%8 = bh%8 -> all q-tiles of a head on one XCD.
// Single-buffer gload_lds staging (r4 form), pre-swizzled source slots.
// log2-domain softmax (Q pre-scaled by 0.125*log2e), cvt_pk P-pack,
// per-lane partial row-sums, defer-max THR=11.5 (log2 of e^8).
// ---------------------------------------------------------------------------
__global__ __launch_bounds__(256, 2) void attn_kernel(
    const u16* __restrict__ Q, const u16* __restrict__ K,
    const u16* __restrict__ Vt, u16* __restrict__ O)
{
  __shared__ __align__(16) u16 Ks[64 * 64];       // [key][d] swizzled slots
  __shared__ __align__(16) u16 Vs[64 * 64];       // [d][key] swizzled slots
  __shared__ __align__(16) u16 Pl[4 * 32 * 72];   // per-wave [qrow][key]

  const int tid = threadIdx.x, lane = tid & 63, wid = tid >> 6;
  const int lg = lane >> 4, lc = lane & 15;
  const int bh = blockIdx.x;       // [0,128)
  const int qt = blockIdx.y;       // [0,8)
  const size_t base = (size_t)bh * 65536;
  const u16* Qp = Q + base;
  const u16* Kp = K + base;
  const u16* Vp = Vt + base;       // [64][1024]

  // Q fragments (B-operand), pre-scaled by 0.125 * log2(e)
  const float QSCALE = 0.125f * 1.44269504f;
  bf16x8 qf[2][2];
  #pragma unroll
  for (int f = 0; f < 2; ++f) {
    const u16* qsrc = Qp + (size_t)(qt * 128 + wid * 32 + f * 16 + lc) * 64 + lg * 8;
    #pragma unroll
    for (int ks = 0; ks < 2; ++ks) {
      u16x8 raw = *(const u16x8*)(qsrc + ks * 32);
      bf16x8 t;
      #pragma unroll
      for (int j = 0; j < 8; ++j) t[j] = (short)f2bf(bf2f(raw[j]) * QSCALE);
      qf[f][ks] = t;
    }
  }

  f32x4 o[2][4];
  #pragma unroll
  for (int f = 0; f < 2; ++f)
    #pragma unroll
    for (int d = 0; d < 4; ++d) o[f][d] = (f32x4){0.f, 0.f, 0.f, 0.f};
  float m_r[2] = {-1e30f, -1e30f};  // log2 domain
  float l_r[2] = {0.f, 0.f};        // per-lane partial row sums

  // staging: wave w stages rows [w*16, w*16+16) of each tile.
  const int srow  = lane >> 3;               // 0..7
  const int sslot = (lane & 7) ^ srow;       // pre-swizzled 16B slot
  const u16* gK0 = Kp + (size_t)(wid * 16 + srow) * 64 + sslot * 8;
  const u16* gV0 = Vp + (size_t)(wid * 16 + srow) * 1024 + sslot * 8;
  u16* lK0 = Ks + wid * 1024;
  u16* lV0 = Vs + wid * 1024;

  // read-side swizzled column offsets (elems): slot = ks*4+lg, xor row&7
  const int xr = lc & 7;
  const int cof0 = ((0 + lg) ^ xr) * 8;
  const int cof1 = ((4 + lg) ^ xr) * 8;
  const int prow = (wid * 32 + lc) * 72;

  for (int kt = 0; kt < 16; ++kt) {
    gload16(gK0 + kt * 4096, lK0, lane);
    gload16(gK0 + kt * 4096 + 512, lK0 + 512, lane);
    gload16(gV0 + kt * 64, lV0, lane);
    gload16(gV0 + 8192 + kt * 64, lV0 + 512, lane);
    __syncthreads();

    // S^T = K @ Q (log2-scaled): lane holds q-row f*16+lc, keys kb*16+lg*4+c
    f32x4 s[2][4];
    #pragma unroll
    for (int f = 0; f < 2; ++f)
      #pragma unroll
      for (int kb = 0; kb < 4; ++kb) s[f][kb] = (f32x4){0.f, 0.f, 0.f, 0.f};
    #pragma unroll
    for (int ks = 0; ks < 2; ++ks) {
      const int co = ks ? cof1 : cof0;
      #pragma unroll
      for (int kb = 0; kb < 4; ++kb) {
        bf16x8 kfr = *(const bf16x8*)(Ks + (kb * 16 + lc) * 64 + co);
        s[0][kb] = __builtin_amdgcn_mfma_f32_16x16x32_bf16(kfr, qf[0][ks], s[0][kb], 0, 0, 0);
        s[1][kb] = __builtin_amdgcn_mfma_f32_16x16x32_bf16(kfr, qf[1][ks], s[1][kb], 0, 0, 0);
      }
    }

    // online softmax (log2 domain) with defer-max; P pack+store per-wave
    #pragma unroll
    for (int f = 0; f < 2; ++f) {
      f32x4 t01, t23;
      #pragma unroll
      for (int c = 0; c < 4; ++c) {
        t01[c] = fmaxf(s[f][0][c], s[f][1][c]);
        t23[c] = fmaxf(s[f][2][c], s[f][3][c]);
      }
      float t = fmaxf(fmaxf(fmaxf(t01[0], t01[1]), fmaxf(t01[2], t01[3])),
                      fmaxf(fmaxf(t23[0], t23[1]), fmaxf(t23[2], t23[3])));
      t = fmaxf(t, __shfl_xor(t, 16));
      t = fmaxf(t, __shfl_xor(t, 32));

      if (!__all((t - m_r[f]) <= 11.5f)) {          // max grew: rescale
        float nm = fmaxf(m_r[f], t);
        float sc = fexp2(m_r[f] - nm);
        m_r[f] = nm;
        l_r[f] *= sc;
        #pragma unroll
        for (int r = 0; r < 4; ++r) {
          float scr = __shfl(sc, lg * 4 + r, 16);
          #pragma unroll
          for (int d = 0; d < 4; ++d) o[f][d][r] *= scr;
        }
      }

      float lsum = 0.f;
      #pragma unroll
      for (int kb = 0; kb < 4; ++kb) {
        f32x4 p;
        #pragma unroll
        for (int c = 0; c < 4; ++c) {
          p[c] = fexp2(s[f][kb][c] - m_r[f]);
          lsum += p[c];
        }
        u32x2 w = { cvt_pk_bf16(p[0], p[1]), cvt_pk_bf16(p[2], p[3]) };
        *(u32x2*)(Pl + prow + f * 1152 + kb * 16 + lg * 4) = w;
      }
      l_r[f] += lsum;   // partial; cross-lane reduce in epilogue
    }

    // PV: O += P @ V^T-frags (compiler orders Pl writes->reads; in-order DS)
    bf16x8 pa[2][2];
    #pragma unroll
    for (int f = 0; f < 2; ++f)
      #pragma unroll
      for (int ks = 0; ks < 2; ++ks)
        pa[f][ks] = *(const bf16x8*)(Pl + prow + f * 1152 + ks * 32 + lg * 8);
    #pragma unroll
    for (int d = 0; d < 4; ++d) {
      #pragma unroll
      for (int ks = 0; ks < 2; ++ks) {
        const int co = ks ? cof1 : cof0;
        bf16x8 vfr = *(const bf16x8*)(Vs + (d * 16 + lc) * 64 + co);
        o[0][d] = __builtin_amdgcn_mfma_f32_16x16x32_bf16(pa[0][ks], vfr, o[0][d], 0, 0, 0);
        o[1][d] = __builtin_amdgcn_mfma_f32_16x16x32_bf16(pa[1][ks], vfr, o[1][d], 0, 0, 0);
      }
    }
    __syncthreads();
  }

  // finalize: cross-lane l reduce, divide, store bf16 [B][N][C]
  const int b = bh >> 4, h = bh & 15;
  #pragma unroll
  for (int f = 0; f < 2; ++f) {
    float t = l_r[f];
    t += __shfl_xor(t, 16);
    t += __shfl_xor(t, 32);
    float linv = 1.0f / t;
    #pragma unroll
    for (int r = 0; r < 4; ++r) {
      float li = __shfl(linv, lg * 4 + r, 16);
      int n = qt * 128 + wid * 32 + f * 16 + lg * 4 + r;
      u16* dst = O + ((size_t)b * 1024 + n) * 1024 + h * 64 + lc;
      #pragma unroll
      for (int d = 0; d < 4; ++d) dst[d * 16] = f2bf(o[f][d][r] * li);
    }
  }
}

// ---------------------------------------------------------------------------
// Projection GEMM (m97 structure), unchanged.
// ---------------------------------------------------------------------------
__global__ __launch_bounds__(256, 2) void proj_gemm2(
    const u16* __restrict__ Ab, const u16* __restrict__ Wt,
    const float* __restrict__ bias, float* __restrict__ Out)
{
  constexpr int KD = 1024, NCOL = 1024;
  __shared__ __align__(16) u16 As[128 * 32];
  __shared__ __align__(16) u16 Bs[128 * 32];

  const int tid = threadIdx.x;
  const int lane = tid & 63, wid = tid >> 6;
  const int wr = wid >> 1, wc = wid & 1;
  const int lg = lane >> 4, lc = lane & 15;
  const int row0 = blockIdx.x * 128, col0 = blockIdx.y * 128;

  f32x4 acc[4][4];
  #pragma unroll
  for (int m = 0; m < 4; ++m)
    #pragma unroll
    for (int n = 0; n < 4; ++n) acc[m][n] = (f32x4){0.f, 0.f, 0.f, 0.f};

  const int l4 = lane >> 2, ls = (lane & 3) * 8;
  const u16* gA0 = Ab + (size_t)(row0 + wid * 16 + l4) * KD + ls;
  const u16* gB0 = Wt + (size_t)(col0 + wid * 16 + l4) * KD + ls;
  u16* lA0 = As + wid * 512;
  u16* lB0 = Bs + wid * 512;

  for (int k0 = 0; k0 < KD; k0 += 32) {
    gload16(gA0 + k0, lA0, lane);
    gload16(gA0 + 64 * KD + k0, lA0 + 2048, lane);
    gload16(gB0 + k0, lB0, lane);
    gload16(gB0 + 64 * KD + k0, lB0 + 2048, lane);
    __syncthreads();

    bf16x8 a[4], b[4];
    #pragma unroll
    for (int m = 0; m < 4; ++m)
      a[m] = *(const bf16x8*)(As + (wr * 64 + m * 16 + lc) * 32 + lg * 8);
    #pragma unroll
    for (int n = 0; n < 4; ++n)
      b[n] = *(const bf16x8*)(Bs + (wc * 64 + n * 16 + lc) * 32 + lg * 8);
    #pragma unroll
    for (int m = 0; m < 4; ++m)
      #pragma unroll
      for (int n = 0; n < 4; ++n)
        acc[m][n] = __builtin_amdgcn_mfma_f32_16x16x32_bf16(a[m], b[n], acc[m][n], 0, 0, 0);
    __syncthreads();
  }

  #pragma unroll
  for (int m = 0; m < 4; ++m) {
    #pragma unroll
    for (int n = 0; n < 4; ++n) {
      #pragma unroll
      for (int r = 0; r < 4; ++r) {
        int gr = row0 + wr * 64 + m * 16 + lg * 4 + r;
        int gc = col0 + wc * 64 + n * 16 + lc;
        Out[(size_t)gr * NCOL + gc] = acc[m][n][r] + bias[gc];
      }
    }
  }
}

// ---------------------------------------------------------------------------
extern "C" void kernel_launch(void* const* d_in, const int* in_sizes, int n_in,
                              void* d_out, int out_size, void* d_ws, size_t ws_size,
                              hipStream_t stream) {
  const float* x     = (const float*)d_in[0];
  const float* W_qkv = (const float*)d_in[1];
  const float* b_qkv = (const float*)d_in[2];
  const float* W_prj = (const float*)d_in[3];
  const float* b_prj = (const float*)d_in[4];
  float* out = (float*)d_out;

  const size_t SEG = (size_t)8192 * 1024;   // 8388608 elems (u16)
  char* ws = (char*)d_ws;                   // needs ~59 MiB
  u16* Xb  = (u16*)ws;                      // dead after qkv
  u16* Ab  = Xb;                            // alias: attn output
  u16* VtG = (u16*)(ws + SEG * 2);          // V^T [bh][64][1024]
  u16* Wqt = (u16*)(ws + SEG * 4);
  u16* Wpt = Wqt + (size_t)3072 * 1024;
  u16* Vr  = (u16*)(ws + 41943040);         // V row-major
  u16* Qb  = (u16*)d_out;                   // d_out as scratch
  u16* Kb  = Qb + SEG;

  convert_f32_bf16<<<4096, 256, 0, stream>>>(x, Xb);
  transpose_w<<<dim3(48, 16), 256, 0, stream>>>(W_qkv, Wqt, 1024, 3072);
  transpose_w<<<dim3(16, 16), 256, 0, stream>>>(W_prj, Wpt, 1024, 1024);
  qkv_gemm2<<<dim3(64, 24), 256, 0, stream>>>(Xb, Wqt, b_qkv, Qb, Kb, Vr);
  v_transpose<<<2048, 256, 0, stream>>>(Vr, VtG);
  attn_kernel<<<dim3(128, 8), 256, 0, stream>>>(Qb, Kb, VtG, Ab);
  proj_gemm2<<<dim3(64, 8), 256, 0, stream>>>(Ab, Wpt, b_prj, out);
}